// Round 2
// baseline (802.883 us; speedup 1.0000x reference)
//
#include <hip/hip_runtime.h>
#include <hip/hip_bf16.h>
#include <stdint.h>

// MoE routed GEMM: out[i] = x[i] @ W[e_i] + b[e_i]
// B=8192 tokens, D=2048, E=8 experts. Inputs fp32; compute bf16 MFMA.
// R1: gemm at m97 plateau (934 TF); this round rewrites the ~325us of prep:
//   4 launches instead of 7, 16B stores in the W transpose, fused scatter+gather.

#define B_TOK 8192
#define DIM   2048
#define NEXP  8
#define BM 128
#define BN 128
#define BK 32

typedef __attribute__((ext_vector_type(4))) float f32x4;
typedef __attribute__((ext_vector_type(8))) short s16x8;

// RNE float->bf16
__device__ __forceinline__ uint32_t f2bf(float f) {
    uint32_t u = __float_as_uint(f);
    uint32_t r = u + 0x7fffu + ((u >> 16) & 1u);
    return r >> 16;
}

__device__ __forceinline__ void async16(const void* g, void* l) {
    __builtin_amdgcn_global_load_lds(
        (const __attribute__((address_space(1))) uint32_t*)g,
        (__attribute__((address_space(3))) uint32_t*)l, 16, 0, 0);
}

// ---- routing pass 1: histogram + scan + cursor init, ONE block ----------
// meta: [0..8) unused, [8..16) cursors, [16..25) offsets
__global__ void k_hist(const int* __restrict__ idx, int* meta) {
    __shared__ int h[NEXP];
    int t = threadIdx.x;  // 256
    if (t < NEXP) h[t] = 0;
    __syncthreads();
    int c[NEXP] = {0, 0, 0, 0, 0, 0, 0, 0};
    #pragma unroll
    for (int i = 0; i < B_TOK / 256; ++i) {
        int e = idx[t + i * 256];
        #pragma unroll
        for (int k = 0; k < NEXP; ++k) c[k] += (e == k) ? 1 : 0;
    }
    #pragma unroll
    for (int k = 0; k < NEXP; ++k) {
        int v = c[k];
        #pragma unroll
        for (int s = 32; s > 0; s >>= 1) v += __shfl_down(v, s, 64);
        if ((t & 63) == 0) atomicAdd(&h[k], v);
    }
    __syncthreads();
    if (t == 0) {
        int off = 0;
        #pragma unroll
        for (int e = 0; e < NEXP; ++e) {
            meta[16 + e] = off; off += h[e];
            meta[8 + e] = 0;  // scatter cursors
        }
        meta[16 + NEXP] = off;
    }
}

// ---- routing pass 2 fused with gather: one block per token ---------------
// thread 0 claims the destination slot; 256 threads copy+convert the row.
__global__ __launch_bounds__(256) void k_scatgat(
    const float* __restrict__ x, const int* __restrict__ idx, int* meta,
    int* __restrict__ perm, uint16_t* __restrict__ xs) {
    __shared__ int sp;
    int tok = blockIdx.x;
    if (threadIdx.x == 0) {
        int e = idx[tok];
        int pos = atomicAdd(&meta[8 + e], 1);
        int p = meta[16 + e] + pos;
        perm[p] = tok;
        sp = p;
    }
    __syncthreads();
    int p = sp, t = threadIdx.x;
    const float4* xin = (const float4*)(x + (size_t)tok * DIM);
    float4 a = xin[2 * t];
    float4 c = xin[2 * t + 1];
    uint4 o;
    o.x = f2bf(a.x) | (f2bf(a.y) << 16);
    o.y = f2bf(a.z) | (f2bf(a.w) << 16);
    o.z = f2bf(c.x) | (f2bf(c.y) << 16);
    o.w = f2bf(c.z) | (f2bf(c.w) << 16);
    *(uint4*)(xs + (size_t)p * DIM + t * 8) = o;
}

// ---- W[e][d][o] fp32 -> Wt[e][o][d] bf16, 16B loads + 16B stores ---------
// 128d x 64o tile per block. LDS stride 66 (+2 pad): phase-1 b32 writes
// <=2-way, phase-2 u16 reads ~8-way (2.9x) but LDS is not the bound here.
__global__ __launch_bounds__(256) void k_wt(const float* __restrict__ W,
                                            uint16_t* __restrict__ Wt) {
    __shared__ uint16_t tile[128][66];
    int e = blockIdx.z, d0 = blockIdx.x * 128, o0 = blockIdx.y * 64;
    const float* Wp = W + ((size_t)e * DIM + d0) * DIM + o0;
    int t = threadIdx.x;
    int lr = t >> 4;            // 0..15: row within pass
    int c4 = (t & 15) * 4;      // col
    #pragma unroll
    for (int p = 0; p < 8; ++p) {
        int d = p * 16 + lr;
        float4 v = *(const float4*)(Wp + (size_t)d * DIM + c4);
        *(uint32_t*)&tile[d][c4]     = f2bf(v.x) | (f2bf(v.y) << 16);
        *(uint32_t*)&tile[d][c4 + 2] = f2bf(v.z) | (f2bf(v.w) << 16);
    }
    __syncthreads();
    uint16_t* Wo = Wt + ((size_t)e * DIM + o0) * DIM + d0;
    int dc = (t & 15) * 8;      // 8-elem d-chunk
    int ob = t >> 4;            // 0..15
    #pragma unroll
    for (int q = 0; q < 4; ++q) {
        int o = q * 16 + ob;
        uint32_t w[4];
        #pragma unroll
        for (int j = 0; j < 4; ++j)
            w[j] = (uint32_t)tile[dc + 2 * j][o] | ((uint32_t)tile[dc + 2 * j + 1][o] << 16);
        *(uint4*)(Wo + (size_t)o * DIM + dc) = *(uint4*)w;  // 16 lanes -> 256B contig
    }
}

// ---- per-expert-segment GEMM (m97 structure, unchanged from R1) ----------
__global__ __launch_bounds__(256) void k_gemm(
    const uint16_t* __restrict__ xs, const uint16_t* __restrict__ Wt,
    const float* __restrict__ bias, const int* __restrict__ meta,
    const int* __restrict__ perm, float* __restrict__ out) {
    __shared__ uint16_t As[BM * BK];
    __shared__ uint16_t Bs[BN * BK];
    __shared__ int permS[BM];

    int id = blockIdx.y;
    int e = -1, seg0 = 0, segc = 0;
    for (int i = 0; i < NEXP; ++i) {
        int o0 = meta[16 + i], o1 = meta[16 + i + 1];
        int tiles = (o1 - o0 + BM - 1) / BM;
        if (id < tiles) { e = i; seg0 = o0; segc = o1 - o0; break; }
        id -= tiles;
    }
    if (e < 0) return;
    int m0 = seg0 + id * BM;
    int valid = segc - id * BM; if (valid > BM) valid = BM;
    int n0 = blockIdx.x * BN;

    int tid = threadIdx.x;
    if (tid < BM) permS[tid] = (tid < valid) ? perm[m0 + tid] : 0;

    int wave = tid >> 6, lane = tid & 63;
    int wm = (wave >> 1) * 64, wn = (wave & 1) * 64;
    int lr = lane & 15, quad = lane >> 4;

    f32x4 acc[4][4] = {};

    const uint16_t* aG = xs + (size_t)m0 * DIM;
    const uint16_t* bG = Wt + ((size_t)e * DIM + n0) * DIM;

    for (int k0 = 0; k0 < DIM; k0 += BK) {
        #pragma unroll
        for (int ro = 0; ro < 2; ++ro) {
            int ch = ro * 256 + tid;
            int row = ch >> 2, kc = (ch & 3) * 8;
            async16(aG + (size_t)row * DIM + k0 + kc, As + ch * 8);
            async16(bG + (size_t)row * DIM + k0 + kc, Bs + ch * 8);
        }
        __syncthreads();

        s16x8 af[4], bf[4];
        #pragma unroll
        for (int i = 0; i < 4; ++i)
            af[i] = *(const s16x8*)(As + (wm + i * 16 + lr) * BK + quad * 8);
        #pragma unroll
        for (int i = 0; i < 4; ++i)
            bf[i] = *(const s16x8*)(Bs + (wn + i * 16 + lr) * BK + quad * 8);
        #pragma unroll
        for (int i = 0; i < 4; ++i)
            #pragma unroll
            for (int j = 0; j < 4; ++j)
                acc[i][j] = __builtin_amdgcn_mfma_f32_16x16x32_bf16(af[i], bf[j], acc[i][j], 0, 0, 0);
        __syncthreads();
    }

    #pragma unroll
    for (int j = 0; j < 4; ++j) {
        int col = n0 + wn + j * 16 + lr;
        float bv = bias[e * DIM + col];
        #pragma unroll
        for (int i = 0; i < 4; ++i) {
            #pragma unroll
            for (int r = 0; r < 4; ++r) {
                int lrow = wm + i * 16 + quad * 4 + r;
                if (lrow < valid) {
                    out[(size_t)permS[lrow] * DIM + col] = acc[i][j][r] + bv;
                }
            }
        }
    }
}

// ---- launch --------------------------------------------------------------
// ws: [0,256) meta | [256,33024) perm | [64K, +34.1MB) xs (B+BM rows padded)
//     | Wt 67.1MB. ~96.6 MiB total.
extern "C" void kernel_launch(void* const* d_in, const int* in_sizes, int n_in,
                              void* d_out, int out_size, void* d_ws, size_t ws_size,
                              hipStream_t stream) {
    const float* x    = (const float*)d_in[0];
    const float* W    = (const float*)d_in[1];
    const float* bias = (const float*)d_in[2];
    const int*   idx  = (const int*)d_in[3];
    float* out = (float*)d_out;

    char* ws = (char*)d_ws;
    int* meta = (int*)ws;
    int* perm = (int*)(ws + 256);
    uint16_t* xs = (uint16_t*)(ws + 65536);
    uint16_t* Wt = (uint16_t*)(ws + 65536 + (size_t)(B_TOK + BM) * DIM * 2);

    k_hist<<<1, 256, 0, stream>>>(idx, meta);
    k_scatgat<<<B_TOK, 256, 0, stream>>>(x, idx, meta, perm, xs);
    k_wt<<<dim3(DIM / 128, DIM / 64, NEXP), 256, 0, stream>>>(W, Wt);
    k_gemm<<<dim3(DIM / BN, B_TOK / BM + NEXP, 1), 256, 0, stream>>>(
        xs, Wt, bias, meta, perm, out);
}

// Round 3
// 413.724 us; speedup vs baseline: 1.9406x; 1.9406x over previous
//
#include <hip/hip_runtime.h>
#include <hip/hip_bf16.h>
#include <stdint.h>

// MoE routed GEMM: out[i] = x[i] @ W[e_i] + b[e_i]
// B=8192 tokens, D=2048, E=8 experts. Inputs fp32; compute bf16 MFMA.
// R2 lesson: per-block global atomics serialized (410us). R3: deterministic
// single-block routing (no atomics), standalone gather, swizzled-LDS W
// transpose with b128 reads + 16B stores. GEMM unchanged (m97 plateau).

#define B_TOK 8192
#define DIM   2048
#define NEXP  8
#define BM 128
#define BN 128
#define BK 32

typedef __attribute__((ext_vector_type(4))) float f32x4;
typedef __attribute__((ext_vector_type(8))) short s16x8;

// RNE float->bf16
__device__ __forceinline__ uint32_t f2bf(float f) {
    uint32_t u = __float_as_uint(f);
    uint32_t r = u + 0x7fffu + ((u >> 16) & 1u);
    return r >> 16;
}

__device__ __forceinline__ void async16(const void* g, void* l) {
    __builtin_amdgcn_global_load_lds(
        (const __attribute__((address_space(1))) uint32_t*)g,
        (__attribute__((address_space(3))) uint32_t*)l, 16, 0, 0);
}

// ---- routing: ONE block, zero atomics, deterministic ---------------------
// Each thread owns 32 contiguous tokens: local hist -> LDS column scan ->
// replay tokens writing perm. meta[16..24] = segment offsets, [24] = total.
__global__ __launch_bounds__(256) void k_route(const int* __restrict__ idx,
                                               int* __restrict__ meta,
                                               int* __restrict__ perm) {
    __shared__ int cnt[256][9];   // stride 9: per-lane banks spread (gcd(9,32)=1)
    __shared__ int offS[NEXP + 1];
    int t = threadIdx.x;
    int myIdx[32];
    #pragma unroll
    for (int i = 0; i < 32; ++i) myIdx[i] = idx[t * 32 + i];
    int c[NEXP] = {0, 0, 0, 0, 0, 0, 0, 0};
    #pragma unroll
    for (int i = 0; i < 32; ++i) {
        int e = myIdx[i];
        #pragma unroll
        for (int k = 0; k < NEXP; ++k) c[k] += (e == k) ? 1 : 0;
    }
    #pragma unroll
    for (int k = 0; k < NEXP; ++k) cnt[t][k] = c[k];
    __syncthreads();
    if (t < NEXP) {                      // 8 threads: exclusive scan down column t
        int run = 0;
        for (int j = 0; j < 256; ++j) { int v = cnt[j][t]; cnt[j][t] = run; run += v; }
        offS[t] = run;                   // expert total (temp)
    }
    __syncthreads();
    if (t == 0) {
        int off = 0;
        #pragma unroll
        for (int e = 0; e < NEXP; ++e) {
            int v = offS[e];
            offS[e] = off; meta[16 + e] = off; off += v;
        }
        offS[NEXP] = off; meta[16 + NEXP] = off;
    }
    __syncthreads();
    int base[NEXP];
    #pragma unroll
    for (int k = 0; k < NEXP; ++k) base[k] = offS[k] + cnt[t][k];
    #pragma unroll
    for (int i = 0; i < 32; ++i) {
        int e = myIdx[i];
        int pos = 0;
        #pragma unroll
        for (int k = 0; k < NEXP; ++k) pos += (e == k) ? base[k] : 0;
        perm[pos] = t * 32 + i;
        #pragma unroll
        for (int k = 0; k < NEXP; ++k) base[k] += (e == k) ? 1 : 0;
    }
}

// ---- gather x into sorted order, fp32 -> bf16 (one row per block) --------
__global__ __launch_bounds__(256) void k_gather(const float* __restrict__ x,
                                                const int* __restrict__ perm,
                                                uint16_t* __restrict__ xs) {
    int p = blockIdx.x;
    int src = perm[p];                   // uniform -> s_load
    int t = threadIdx.x;
    const float4* xin = (const float4*)(x + (size_t)src * DIM);
    float4 a = xin[2 * t];
    float4 c = xin[2 * t + 1];
    uint4 o;
    o.x = f2bf(a.x) | (f2bf(a.y) << 16);
    o.y = f2bf(a.z) | (f2bf(a.w) << 16);
    o.z = f2bf(c.x) | (f2bf(c.y) << 16);
    o.w = f2bf(c.z) | (f2bf(c.w) << 16);
    *(uint4*)(xs + (size_t)p * DIM + t * 8) = o;
}

// ---- W[e][d][o] fp32 -> Wt[e][o][d] bf16 ---------------------------------
// 128d x 64o tile. LDS u32[64 o][65] holds bf16 (d,d+1) pairs at swizzled
// column col' = dp ^ ((o&15)<<2). Verified <=2-way banks both phases;
// phase-2 is ds_read_b128 + global_store_dwordx4.
__global__ __launch_bounds__(256) void k_wt(const float* __restrict__ W,
                                            uint16_t* __restrict__ Wt) {
    __shared__ uint32_t lds[64][65];
    int e = blockIdx.z, d0 = blockIdx.x * 128, o0 = blockIdx.y * 64;
    int t = threadIdx.x;
    const float* Wp = W + ((size_t)e * DIM + d0) * DIM + o0;
    #pragma unroll
    for (int p = 0; p < 4; ++p) {
        int dp = p * 16 + (t >> 4);      // d-pair index 0..63
        int oc = (t & 15) * 4;           // o base
        const float* r0 = Wp + (size_t)(2 * dp) * DIM + oc;
        float4 v0 = *(const float4*)r0;
        float4 v1 = *(const float4*)(r0 + DIM);
        uint32_t w0 = f2bf(v0.x) | (f2bf(v1.x) << 16);
        uint32_t w1 = f2bf(v0.y) | (f2bf(v1.y) << 16);
        uint32_t w2 = f2bf(v0.z) | (f2bf(v1.z) << 16);
        uint32_t w3 = f2bf(v0.w) | (f2bf(v1.w) << 16);
        lds[oc + 0][dp ^ (((oc + 0) & 15) << 2)] = w0;
        lds[oc + 1][dp ^ (((oc + 1) & 15) << 2)] = w1;
        lds[oc + 2][dp ^ (((oc + 2) & 15) << 2)] = w2;
        lds[oc + 3][dp ^ (((oc + 3) & 15) << 2)] = w3;
    }
    __syncthreads();
    uint16_t* Wo = Wt + ((size_t)e * DIM + o0) * DIM + d0;
    #pragma unroll
    for (int q = 0; q < 4; ++q) {
        int o = q * 16 + (t >> 4);
        int cb = ((t & 15) * 4) ^ ((o & 15) << 2);  // contiguous 4 u32 from here
        uint4 w = *(const uint4*)&lds[o][cb];
        *(uint4*)(Wo + (size_t)o * DIM + (t & 15) * 8) = w;
    }
}

// ---- per-expert-segment GEMM (m97 structure, unchanged) ------------------
__global__ __launch_bounds__(256) void k_gemm(
    const uint16_t* __restrict__ xs, const uint16_t* __restrict__ Wt,
    const float* __restrict__ bias, const int* __restrict__ meta,
    const int* __restrict__ perm, float* __restrict__ out) {
    __shared__ uint16_t As[BM * BK];
    __shared__ uint16_t Bs[BN * BK];
    __shared__ int permS[BM];

    int id = blockIdx.y;
    int e = -1, seg0 = 0, segc = 0;
    for (int i = 0; i < NEXP; ++i) {
        int o0 = meta[16 + i], o1 = meta[16 + i + 1];
        int tiles = (o1 - o0 + BM - 1) / BM;
        if (id < tiles) { e = i; seg0 = o0; segc = o1 - o0; break; }
        id -= tiles;
    }
    if (e < 0) return;
    int m0 = seg0 + id * BM;
    int valid = segc - id * BM; if (valid > BM) valid = BM;
    int n0 = blockIdx.x * BN;

    int tid = threadIdx.x;
    if (tid < BM) permS[tid] = (tid < valid) ? perm[m0 + tid] : 0;

    int wave = tid >> 6, lane = tid & 63;
    int wm = (wave >> 1) * 64, wn = (wave & 1) * 64;
    int lr = lane & 15, quad = lane >> 4;

    f32x4 acc[4][4] = {};

    const uint16_t* aG = xs + (size_t)m0 * DIM;
    const uint16_t* bG = Wt + ((size_t)e * DIM + n0) * DIM;

    for (int k0 = 0; k0 < DIM; k0 += BK) {
        #pragma unroll
        for (int ro = 0; ro < 2; ++ro) {
            int ch = ro * 256 + tid;
            int row = ch >> 2, kc = (ch & 3) * 8;
            async16(aG + (size_t)row * DIM + k0 + kc, As + ch * 8);
            async16(bG + (size_t)row * DIM + k0 + kc, Bs + ch * 8);
        }
        __syncthreads();

        s16x8 af[4], bf[4];
        #pragma unroll
        for (int i = 0; i < 4; ++i)
            af[i] = *(const s16x8*)(As + (wm + i * 16 + lr) * BK + quad * 8);
        #pragma unroll
        for (int i = 0; i < 4; ++i)
            bf[i] = *(const s16x8*)(Bs + (wn + i * 16 + lr) * BK + quad * 8);
        #pragma unroll
        for (int i = 0; i < 4; ++i)
            #pragma unroll
            for (int j = 0; j < 4; ++j)
                acc[i][j] = __builtin_amdgcn_mfma_f32_16x16x32_bf16(af[i], bf[j], acc[i][j], 0, 0, 0);
        __syncthreads();
    }

    #pragma unroll
    for (int j = 0; j < 4; ++j) {
        int col = n0 + wn + j * 16 + lr;
        float bv = bias[e * DIM + col];
        #pragma unroll
        for (int i = 0; i < 4; ++i) {
            #pragma unroll
            for (int r = 0; r < 4; ++r) {
                int lrow = wm + i * 16 + quad * 4 + r;
                if (lrow < valid) {
                    out[(size_t)permS[lrow] * DIM + col] = acc[i][j][r] + bv;
                }
            }
        }
    }
}

// ---- launch --------------------------------------------------------------
// ws: [0,256) meta | [256,33024) perm | [64K, +34.1MB) xs (B+BM rows padded
// so tail-tile staging stays in-bounds) | Wt 67.1MB. ~96.6 MiB total.
extern "C" void kernel_launch(void* const* d_in, const int* in_sizes, int n_in,
                              void* d_out, int out_size, void* d_ws, size_t ws_size,
                              hipStream_t stream) {
    const float* x    = (const float*)d_in[0];
    const float* W    = (const float*)d_in[1];
    const float* bias = (const float*)d_in[2];
    const int*   idx  = (const int*)d_in[3];
    float* out = (float*)d_out;

    char* ws = (char*)d_ws;
    int* meta = (int*)ws;
    int* perm = (int*)(ws + 256);
    uint16_t* xs = (uint16_t*)(ws + 65536);
    uint16_t* Wt = (uint16_t*)(ws + 65536 + (size_t)(B_TOK + BM) * DIM * 2);

    k_route<<<1, 256, 0, stream>>>(idx, meta, perm);
    k_gather<<<B_TOK, 256, 0, stream>>>(x, perm, xs);
    k_wt<<<dim3(DIM / 128, DIM / 64, NEXP), 256, 0, stream>>>(W, Wt);
    k_gemm<<<dim3(DIM / BN, B_TOK / BM + NEXP, 1), 256, 0, stream>>>(
        xs, Wt, bias, meta, perm, out);
}